// Round 7
// baseline (68.420 us; speedup 1.0000x reference)
//
#include <hip/hip_runtime.h>
#include <hip/hip_bf16.h>
#include <math.h>

#define KS 3
#define C_IN 64
#define F_OUT 128
#define NPOS 9
#define HH 128
#define WWID 128
#define NB 16

typedef __attribute__((ext_vector_type(8))) short bf16x8;
typedef __attribute__((ext_vector_type(4))) float f32x4;

__device__ __forceinline__ unsigned short f2bf(float f) {
  union { float f; unsigned u; } v; v.f = f;
  unsigned u = v.u;
  return (unsigned short)((u + 0x7FFFu + ((u >> 16) & 1u)) >> 16);  // RNE
}
__device__ __forceinline__ unsigned cvtpk(float lo, float hi) {
  unsigned r;
  asm("v_cvt_pk_bf16_f32 %0, %1, %2" : "=v"(r) : "v"(lo), "v"(hi));
  return r;
}
__device__ __forceinline__ bf16x8 pack8(float4 v0, float4 v1) {
  union { unsigned u[4]; bf16x8 v; } r;
  r.u[0] = cvtpk(v0.x, v0.y); r.u[1] = cvtpk(v0.z, v0.w);
  r.u[2] = cvtpk(v1.x, v1.y); r.u[3] = cvtpk(v1.z, v1.w);
  return r.v;
}

// ---- Kernel 1: AW (bf16 in {-1,0,1}) in (ch, p-group) phase-sliced swizzled
// layout. Element (p,f,c): ch=c>>5, cg=(c>>3)&3, ps=(cg+((f&15)>>1))&3,
// pg = p>=5, pl = p - pg*5, sl = ch*2+pg ->
// off = ((sl*5 + pl)*128 + f)*32 + ps*8 + (c&7).
// Each slice (<=40960 B) is a linear LDS copy; conv's ps-swizzled
// ds_read_b128 is the r5-verified 0-conflict pattern.
__global__ void compute_aw(const float* __restrict__ kern,
                           const float* __restrict__ D,
                           const float* __restrict__ gu,
                           unsigned short* __restrict__ AWsw) {
  int t = blockIdx.x * blockDim.x + threadIdx.x;
  if (t >= F_OUT * C_IN) return;
  int base = t * NPOS;
  float pert[NPOS];
#pragma unroll
  for (int n = 0; n < NPOS; ++n) {
    float u = gu[base + n];
    float g = -0.001f * logf(-logf(u + 1e-20f) + 1e-20f);
    pert[n] = D[base + n] + g;
  }
  unsigned mask = 0;
#pragma unroll
  for (int k = 0; k < 4; ++k) {
    int best = 0; float bv = -INFINITY;
#pragma unroll
    for (int n = 0; n < NPOS; ++n) {
      bool taken = (mask >> n) & 1;
      if (!taken && pert[n] > bv) { bv = pert[n]; best = n; }
    }
    mask |= (1u << best);
  }
#pragma unroll
  for (int n = 0; n < NPOS; ++n) {
    int L = base + n;
    float kv = kern[L];
    float s = (kv > 0.f) ? 1.f : ((kv < 0.f) ? -1.f : 0.f);
    float v = ((mask >> n) & 1) ? s : 0.f;
    int f = L & (F_OUT - 1);
    int r = L >> 7;
    int c = r & (C_IN - 1);
    int p = r >> 6;
    int ch = c >> 5;
    int cg = (c >> 3) & 3;
    int ps = (cg + ((f & 15) >> 1)) & 3;
    int pg = (p >= 5) ? 1 : 0;
    int pl = p - pg * 5;
    int sl = ch * 2 + pg;
    int off = ((sl * 5 + pl) * F_OUT + f) * 32 + ps * 8 + (c & 7);
    AWsw[off] = f2bf(v);
  }
}

// ---- Kernel 2: fused implicit-GEMM conv, both operands LDS-resident,
// sized for 2 blocks/CU (74.2 KiB LDS). Block = 2 output rows (M=256),
// 8 waves: wave tile 64(M) x 64(N); 4 phases = ch-half x p-group.
// As: 4 input rows x 130 px x 32 ch (ch-phased, restaged once).
// Bs: 5-position slice, 128 f x 32 ch (restaged 3x).
__global__ __launch_bounds__(512, 4)
void conv2(const float* __restrict__ x,
           const unsigned short* __restrict__ AWsw,
           const float* __restrict__ bias,
           float* __restrict__ out) {
  __shared__ __align__(16) unsigned short As[4 * 130 * 32];  // 33280 B
  __shared__ __align__(16) unsigned short Bs[5 * F_OUT * 32];  // 40960 B

  int tid = threadIdx.x;
  int lane = tid & 63, wave = tid >> 6;
  int lr = lane & 15, lg = lane >> 4;

  int bid = blockIdx.x;
  int wg = (bid & 7) * 128 + (bid >> 3);   // XCD-contiguous (1024 % 8 == 0)
  int n = wg >> 6;
  int h0 = (wg & 63) * 2;

  int ms = wave & 3, fh = wave >> 2;
  int ro = ms >> 1;            // output row within strip
  int mh = ms & 1;             // 64-px half
  int f0 = fh * 64;

  const float* xim = x + ((long long)n * HH) * WWID * C_IN;

  // ---- stage helpers (inlined below)
  // B slice copy: nseg x 512 chunks of 16 B, linear.
#define STAGE_B(SL, NSEG)                                                    \
  {                                                                          \
    const unsigned short* src = AWsw + (SL) * (5 * F_OUT * 32);              \
    _Pragma("unroll")                                                        \
    for (int s = 0; s < (NSEG); ++s) {                                       \
      int ci = s * 512 + tid;                                                \
      *reinterpret_cast<bf16x8*>(Bs + ci * 8) =                              \
          *reinterpret_cast<const bf16x8*>(src + ci * 8);                    \
    }                                                                        \
  }
  // A ch-slice stage: 4 rows x (128 px x 4 cg), one row per iteration.
#define STAGE_A(CH)                                                          \
  {                                                                          \
    _Pragma("unroll")                                                        \
    for (int r = 0; r < 4; ++r) {                                            \
      int hh = h0 - 1 + r;                                                   \
      if ((unsigned)hh < (unsigned)HH) {                                     \
        int px = tid >> 2, cg = tid & 3;                                     \
        const float* sp = xim + (long long)hh * (WWID * C_IN) + px * C_IN +  \
                          (CH) * 32 + cg * 8;                                \
        float4 v0 = *reinterpret_cast<const float4*>(sp);                    \
        float4 v1 = *reinterpret_cast<const float4*>(sp + 4);                \
        int pp = px + 1;                                                     \
        *reinterpret_cast<bf16x8*>(As + r * 4160 + pp * 32 +                 \
                                   (cg ^ (pp & 3)) * 8) = pack8(v0, v1);     \
      }                                                                      \
    }                                                                        \
  }
  // compute one (ch, pgroup) phase: positions pl, full unroll.
#define COMPUTE(PG)                                                          \
  {                                                                          \
    _Pragma("unroll")                                                        \
    for (int pl = 0; pl < ((PG) ? 4 : 5); ++pl) {                            \
      int p = (PG) ? pl + 5 : pl;                                            \
      int i = p / 3, j = p % 3;                                              \
      const char* bp = (const char*)Bs + pl * 8192 + (f0 + lr) * 64 +        \
                       (((lg + (lr >> 1)) & 3) << 4);                        \
      bf16x8 b[4];                                                           \
      _Pragma("unroll")                                                      \
      for (int nf = 0; nf < 4; ++nf)                                         \
        b[nf] = *reinterpret_cast<const bf16x8*>(bp + nf * 1024);            \
      bf16x8 a[4];                                                           \
      _Pragma("unroll")                                                      \
      for (int mfi = 0; mfi < 4; ++mfi) {                                    \
        int px = mh * 64 + mfi * 16 + lr + j;                                \
        a[mfi] = *reinterpret_cast<const bf16x8*>(                           \
            (const char*)As + (ro + i) * 8320 + px * 64 +                    \
            ((lg ^ (px & 3)) << 4));                                         \
      }                                                                      \
      _Pragma("unroll")                                                      \
      for (int mfi = 0; mfi < 4; ++mfi)                                      \
        _Pragma("unroll")                                                    \
        for (int nf = 0; nf < 4; ++nf)                                       \
          acc[mfi][nf] = __builtin_amdgcn_mfma_f32_16x16x32_bf16(            \
              a[mfi], b[nf], acc[mfi][nf], 0, 0, 0);                         \
    }                                                                        \
  }

  // ---- memset As (pads + out-of-image rows)
  bf16x8 z = {};
#pragma unroll
  for (int t = 0; t < 5; ++t) {
    int ci = t * 512 + tid;
    if (ci < 2080) *reinterpret_cast<bf16x8*>(As + ci * 8) = z;
  }
  __syncthreads();

  f32x4 acc[4][4] = {};

  STAGE_A(0)
  STAGE_B(0, 5)
  __syncthreads();
  COMPUTE(0)                      // ch0, p 0-4
  __syncthreads();
  STAGE_B(1, 4)
  __syncthreads();
  COMPUTE(1)                      // ch0, p 5-8
  __syncthreads();
  STAGE_A(1)
  STAGE_B(2, 5)
  __syncthreads();
  COMPUTE(0)                      // ch1, p 0-4
  __syncthreads();
  STAGE_B(3, 4)
  __syncthreads();
  COMPUTE(1)                      // ch1, p 5-8

  // ---- epilogue
  float bi[4];
#pragma unroll
  for (int nf = 0; nf < 4; ++nf) bi[nf] = bias[f0 + nf * 16 + lr];
  int ho = h0 + ro;
  long long ob = ((long long)(n * HH + ho)) * WWID * F_OUT + f0 + lr;
#pragma unroll
  for (int mfi = 0; mfi < 4; ++mfi) {
#pragma unroll
    for (int r = 0; r < 4; ++r) {
      int w = mh * 64 + mfi * 16 + lg * 4 + r;
      float* op = out + ob + (long long)w * F_OUT;
#pragma unroll
      for (int nf = 0; nf < 4; ++nf)
        op[nf * 16] = fmaxf(acc[mfi][nf][r] + bi[nf], 0.f);
    }
  }
#undef STAGE_B
#undef STAGE_A
#undef COMPUTE
}

extern "C" void kernel_launch(void* const* d_in, const int* in_sizes, int n_in,
                              void* d_out, int out_size, void* d_ws, size_t ws_size,
                              hipStream_t stream) {
  const float* x    = (const float*)d_in[0];  // (16,128,128,64)
  const float* kern = (const float*)d_in[1];  // (3,3,64,128)
  const float* bias = (const float*)d_in[2];  // (128,)
  const float* D    = (const float*)d_in[3];  // (3,3,64,128)
  const float* gu   = (const float*)d_in[4];  // (1,128,64,9)

  unsigned short* AWsw = (unsigned short*)d_ws;  // 4 slices x 20480 = 160 KiB

  compute_aw<<<(F_OUT * C_IN + 255) / 256, 256, 0, stream>>>(kern, D, gu, AWsw);

  conv2<<<NB * (HH / 2), 512, 0, stream>>>(x, AWsw, bias, (float*)d_out);
}